// Round 1
// 179.485 us; speedup vs baseline: 1.0684x; 1.0684x over previous
//
#include <hip/hip_runtime.h>

#define NX 512
#define NY 512
#define XY (NX * NY)

typedef float f4 __attribute__((ext_vector_type(4)));

// Cooperative LDS version.
// Block = 512 threads, covers 4 output rows x 512 cols of one batch.
// Phase 1: stage s rows x0-1..x0+4 (6 rows x 3 comps, full y) into LDS (36 KB),
//          plus hold the two outer halo rows (x0-2, x0+5) in registers.
// Phase 2: compute b rows x0-1..x0+4 cooperatively into LDS (12 KB).
// Phase 3: each thread computes one (row, y-float4) output group, 3 comps.
// LDS total 48 KB -> 3 blocks/CU; launch_bounds(512,6) caps VGPR at ~85 so
// 3 blocks (24 waves/CU, 75% occupancy) are actually resident.
__global__ __launch_bounds__(512, 6) void psi11t_kernel(
    const float* __restrict__ s,
    const float* __restrict__ t,
    const float* __restrict__ c0,
    float* __restrict__ out)
{
    __shared__ __align__(16) float s_lds[3 * 6 * NY];  // [c][r][y], r <-> x0-1+r
    __shared__ __align__(16) float b_lds[6 * NY];      // [rb][y], rb <-> x0-1+rb

    // XCD swizzle: each XCD (D%8) gets 512 consecutive logical blocks = 4 whole
    // batches -> halo reuse stays within one XCD's L2.
    const int D = blockIdx.x;                 // 4096 blocks
    const int L = (D & 7) * 512 + (D >> 3);
    const int bidx  = L >> 7;                 // 32 batches
    const int strip = L & 127;                // 128 strips of 4 rows
    const int x0  = strip * 4;
    const int tid = threadIdx.x;
    const int y4g = tid & 127;                // y-group of this thread
    const int yb  = y4g * 4;

    const float* sb = s + (size_t)bidx * 3 * XY;

    // ---- Phase 1: one batched round of global loads ----
    auto ldchunk = [&](int k) -> f4 {
        const int rl = k >> 7;                // 0..17 = c*6 + r
        const int c  = rl / 6;
        const int r  = rl - 6 * c;
        const int xg = (x0 - 1 + r) & (NX - 1);
        return *(const f4*)(sb + (size_t)c * XY + (size_t)xg * NY + (k & 127) * 4);
    };
    f4 st0 = ldchunk(tid);
    f4 st1 = ldchunk(tid + 512);
    f4 st2 = ldchunk(tid + 1024);
    f4 st3 = ldchunk(tid + 1536);
    f4 st4;
    if (tid < 256) st4 = ldchunk(tid + 2048);

    // Outer halo rows, held in registers across the barrier:
    // threads 0..127   -> row x0-2 (up edge for b row rb=0), y = 4*tid
    // threads 128..255 -> row x0+5 (down edge for b row rb=5)
    f4 ge[3];
    if (tid < 256) {
        const int xe = (tid < 128) ? ((x0 - 2) & (NX - 1)) : ((x0 + 5) & (NX - 1));
        const float* re = sb + (size_t)xe * NY + yb;
        #pragma unroll
        for (int c = 0; c < 3; ++c) ge[c] = *(const f4*)(re + (size_t)c * XY);
    }

    *(f4*)&s_lds[(size_t)tid * 4]          = st0;
    *(f4*)&s_lds[(size_t)(tid + 512) * 4]  = st1;
    *(f4*)&s_lds[(size_t)(tid + 1024) * 4] = st2;
    *(f4*)&s_lds[(size_t)(tid + 1536) * 4] = st3;
    if (tid < 256) *(f4*)&s_lds[(size_t)(tid + 2048) * 4] = st4;
    __syncthreads();

    const int ym = (yb + NY - 1) & (NY - 1);  // y-1 (periodic, row-local)
    const int yp = (yb + 4) & (NY - 1);       // y+4 (right scalar)

    // ---- Phase 2: b rows into LDS ----
    // task 1: rb = tid>>7 in 0..3 (all threads)
    {
        const int rb = tid >> 7;
        f4 acc = {0.f, 0.f, 0.f, 0.f};
        #pragma unroll
        for (int c = 0; c < 3; ++c) {
            const float* Sc = &s_lds[(c * 6 + rb) * NY];
            f4 ce = *(const f4*)(Sc + yb);
            f4 up;
            if (rb == 0) up = ge[c];                       // wave-uniform branch
            else         up = *(const f4*)(Sc - NY + yb);
            f4 dn = *(const f4*)(Sc + NY + yb);
            float lf = Sc[ym], rt = Sc[yp];
            f4 shl = {lf, ce[0], ce[1], ce[2]};
            f4 shr = {ce[1], ce[2], ce[3], rt};
            acc += ce * (up + dn + shl + shr);
        }
        *(f4*)&b_lds[rb * NY + yb] = acc;
    }
    // task 2: rb = 4 + (tid>>7) for tid < 256
    if (tid < 256) {
        const int rb = 4 + (tid >> 7);
        f4 acc = {0.f, 0.f, 0.f, 0.f};
        #pragma unroll
        for (int c = 0; c < 3; ++c) {
            const float* Sc = &s_lds[(c * 6 + rb) * NY];
            f4 ce = *(const f4*)(Sc + yb);
            f4 up = *(const f4*)(Sc - NY + yb);
            f4 dn;
            if (rb == 5) dn = ge[c];                       // wave-uniform branch
            else         dn = *(const f4*)(Sc + NY + yb);
            float lf = Sc[ym], rt = Sc[yp];
            f4 shl = {lf, ce[0], ce[1], ce[2]};
            f4 shr = {ce[1], ce[2], ce[3], rt};
            acc += ce * (up + dn + shl + shr);
        }
        *(f4*)&b_lds[rb * NY + yb] = acc;
    }
    __syncthreads();

    // ---- Phase 3: outputs. Output row x = x0 + r; s center row = r+1;
    // b rows r (x-1), r+1 (x), r+2 (x+1).
    const int r = tid >> 7;                   // 0..3
    const int x = x0 + r;

    const float* Bc = &b_lds[(r + 1) * NY];
    f4 bc = *(const f4*)(Bc + yb);
    f4 bu = *(const f4*)(Bc - NY + yb);
    f4 bd = *(const f4*)(Bc + NY + yb);
    float bl = Bc[ym], br = Bc[yp];
    f4 bshl = {bl, bc[0], bc[1], bc[2]};
    f4 bshr = {bc[1], bc[2], bc[3], br};

    f4 G[3], cen[3];
    #pragma unroll
    for (int c = 0; c < 3; ++c) {
        const float* Sc = &s_lds[(c * 6 + r + 1) * NY];
        f4 ce = *(const f4*)(Sc + yb);
        f4 up = *(const f4*)(Sc - NY + yb);
        f4 dn = *(const f4*)(Sc + NY + yb);
        float lf = Sc[ym], rt = Sc[yp];
        f4 shl = {lf, ce[0], ce[1], ce[2]};
        f4 shr = {ce[1], ce[2], ce[3], rt};
        f4 Fs = up + dn + shl + shr;
        G[c] = Fs * bc + up * bu + dn * bd + shl * bshl + shr * bshr;
        cen[c] = ce;
    }

    const float coeff = 2.0f * t[0] * c0[0];
    f4 o0 = (cen[1] * G[2] - cen[2] * G[1]) * coeff;
    f4 o1 = (cen[2] * G[0] - cen[0] * G[2]) * coeff;
    f4 o2 = (cen[0] * G[1] - cen[1] * G[0]) * coeff;

    float* ob = out + (size_t)bidx * 3 * XY + (size_t)x * NY + yb;
    __builtin_nontemporal_store(o0, (f4*)ob);
    __builtin_nontemporal_store(o1, (f4*)(ob + XY));
    __builtin_nontemporal_store(o2, (f4*)(ob + 2 * XY));
}

extern "C" void kernel_launch(void* const* d_in, const int* in_sizes, int n_in,
                              void* d_out, int out_size, void* d_ws, size_t ws_size,
                              hipStream_t stream) {
    const float* s  = (const float*)d_in[0];
    const float* t  = (const float*)d_in[1];
    const float* c0 = (const float*)d_in[2];
    float* out = (float*)d_out;

    psi11t_kernel<<<4096, 512, 0, stream>>>(s, t, c0, out);
}